// Round 1
// baseline (8061.182 us; speedup 1.0000x reference)
//
#include <hip/hip_runtime.h>
#include <math.h>

#define L_ 64
#define M_ 3
#define F_ 32
#define E_ 8
#define HP 1.57079632679489661923f

// 9-way fp64 accumulate: cr[m][k] += a_m * b_k (all compile-time indices)
#define CR_STEP(a0, a1, a2, b0, b1, b2)                          \
    cr[0][0] = fma((double)(a0), (double)(b0), cr[0][0]);        \
    cr[0][1] = fma((double)(a0), (double)(b1), cr[0][1]);        \
    cr[0][2] = fma((double)(a0), (double)(b2), cr[0][2]);        \
    cr[1][0] = fma((double)(a1), (double)(b0), cr[1][0]);        \
    cr[1][1] = fma((double)(a1), (double)(b1), cr[1][1]);        \
    cr[1][2] = fma((double)(a1), (double)(b2), cr[1][2]);        \
    cr[2][0] = fma((double)(a2), (double)(b0), cr[2][0]);        \
    cr[2][1] = fma((double)(a2), (double)(b1), cr[2][1]);        \
    cr[2][2] = fma((double)(a2), (double)(b2), cr[2][2]);

#define ER_STEP(a0, a1, a2, b0, b1, b2)                          \
    er[0][0] = fmaf((a0), (b0), er[0][0]);                       \
    er[0][1] = fmaf((a0), (b1), er[0][1]);                       \
    er[0][2] = fmaf((a0), (b2), er[0][2]);                       \
    er[1][0] = fmaf((a1), (b0), er[1][0]);                       \
    er[1][1] = fmaf((a1), (b1), er[1][1]);                       \
    er[1][2] = fmaf((a1), (b2), er[1][2]);                       \
    er[2][0] = fmaf((a2), (b0), er[2][0]);                       \
    er[2][1] = fmaf((a2), (b1), er[2][1]);                       \
    er[2][2] = fmaf((a2), (b2), er[2][2]);

__global__ __launch_bounds__(128, 2)
void setconv_kernel(const float* __restrict__ x_focal,
                    const float* __restrict__ p_focal,
                    const float* __restrict__ x_neighbor,
                    const float* __restrict__ p_neighbor,
                    const float* __restrict__ edge_nei,
                    const float* __restrict__ x_center,
                    const float* __restrict__ x_support,
                    const float* __restrict__ edge_sup,
                    const float* __restrict__ p_support,
                    float* __restrict__ out,
                    int N)
{
    __shared__ __align__(16) float s_xs[L_][96];   // x_support rows (M*F)
    __shared__ __align__(16) float s_es[L_][24];   // edge_attr_support rows (M*E)
    __shared__ __align__(16) float s_xc[L_][32];   // x_center
    __shared__ float s_scal[L_][12];               // per-l derived scalars

    const int tid = threadIdx.x;
    const int bs  = blockDim.x;

    // -------- cooperative staging of support-side data --------
    for (int i = tid; i < L_ * 96 / 4; i += bs)
        ((float4*)&s_xs[0][0])[i] = ((const float4*)x_support)[i];
    for (int i = tid; i < L_ * 24 / 4; i += bs)
        ((float4*)&s_es[0][0])[i] = ((const float4*)edge_sup)[i];
    for (int i = tid; i < L_ * 32 / 4; i += bs)
        ((float4*)&s_xc[0][0])[i] = ((const float4*)x_center)[i];
    __syncthreads();

    // -------- per-l derived scalars (one thread per l) --------
    if (tid < L_) {
        const int l = tid;
        double ssq = 0.0;
        for (int i = 0; i < 96; ++i) { double v = (double)s_xs[l][i]; ssq += v * v; }
        float esq = 0.f;
        for (int i = 0; i < 24; ++i) esq = fmaf(s_es[l][i], s_es[l][i], esq);
        float csq = 0.f;
        for (int i = 0; i < 32; ++i) csq = fmaf(s_xc[l][i], s_xc[l][i], csq);

        float p0[3], p1[3], p2[3];
        for (int d = 0; d < 3; ++d) {
            p0[d] = p_support[(l * 3 + 0) * 3 + d];
            p1[d] = p_support[(l * 3 + 1) * 3 + d];
            p2[d] = p_support[(l * 3 + 2) * 3 + d];
        }
        float n0 = sqrtf(p0[0]*p0[0] + p0[1]*p0[1] + p0[2]*p0[2]);
        float n1 = sqrtf(p1[0]*p1[0] + p1[1]*p1[1] + p1[2]*p1[2]);
        float n2 = sqrtf(p2[0]*p2[0] + p2[1]*p2[1] + p2[2]*p2[2]);
        float d01 = p0[0]*p1[0] + p0[1]*p1[1] + p0[2]*p1[2];
        float d02 = p0[0]*p2[0] + p0[1]*p2[1] + p0[2]*p2[2];
        float d12 = p1[0]*p2[0] + p1[1]*p2[1] + p1[2]*p2[2];
        float C01 = d01 / fmaxf(n0 * n1, 1e-8f);
        float C02 = d02 / fmaxf(n0 * n2, 1e-8f);
        float C12 = d12 / fmaxf(n1 * n2, 1e-8f);

        s_scal[l][0] = n0;  s_scal[l][1] = n1;  s_scal[l][2] = n2;
        s_scal[l][3] = C01; s_scal[l][4] = C02; s_scal[l][5] = C12;
        s_scal[l][6] = C01*C01 + C02*C02 + C12*C12;   // ang_sup squared-sum (p-invariant)
        s_scal[l][7] = n0*n0 + n1*n1 + n2*n2;         // len_sup squared-sum (p-invariant)
        s_scal[l][8] = (float)ssq;                    // sup_sq (p-invariant)
        s_scal[l][9] = esq;                           // edge_sup squared-sum
        s_scal[l][10] = csq;                          // x_center squared
    }
    __syncthreads();

    const int n = blockIdx.x * bs + tid;
    if (n >= N) return;

    // -------- per-n data into registers --------
    float4 xn4[24], ed4[6], xf4[8];
    {
        const float4* p = (const float4*)(x_neighbor + (size_t)n * 96);
        #pragma unroll
        for (int i = 0; i < 24; ++i) xn4[i] = p[i];
        const float4* q = (const float4*)(edge_nei + (size_t)n * 24);
        #pragma unroll
        for (int i = 0; i < 6; ++i) ed4[i] = q[i];
        const float4* r = (const float4*)(x_focal + (size_t)n * 32);
        #pragma unroll
        for (int i = 0; i < 8; ++i) xf4[i] = r[i];
    }

    // p_rel, intra angles, lengths
    float pr[3][3];
    {
        float pf0 = p_focal[(size_t)n*3 + 0];
        float pf1 = p_focal[(size_t)n*3 + 1];
        float pf2 = p_focal[(size_t)n*3 + 2];
        #pragma unroll
        for (int m = 0; m < 3; ++m) {
            pr[m][0] = p_neighbor[(size_t)n*9 + m*3 + 0] - pf0;
            pr[m][1] = p_neighbor[(size_t)n*9 + m*3 + 1] - pf1;
            pr[m][2] = p_neighbor[(size_t)n*9 + m*3 + 2] - pf2;
        }
    }
    float lenN0 = sqrtf(pr[0][0]*pr[0][0] + pr[0][1]*pr[0][1] + pr[0][2]*pr[0][2]);
    float lenN1 = sqrtf(pr[1][0]*pr[1][0] + pr[1][1]*pr[1][1] + pr[1][2]*pr[1][2]);
    float lenN2 = sqrtf(pr[2][0]*pr[2][0] + pr[2][1]*pr[2][1] + pr[2][2]*pr[2][2]);
    // _intra_angle with roll(+1): ang[0]=<p2,p0>, ang[1]=<p0,p1>, ang[2]=<p1,p2>
    float angN0 = (pr[2][0]*pr[0][0] + pr[2][1]*pr[0][1] + pr[2][2]*pr[0][2]) / fmaxf(lenN2*lenN0, 1e-8f);
    float angN1 = (pr[0][0]*pr[1][0] + pr[0][1]*pr[1][1] + pr[0][2]*pr[1][2]) / fmaxf(lenN0*lenN1, 1e-8f);
    float angN2 = (pr[1][0]*pr[2][0] + pr[1][1]*pr[2][1] + pr[1][2]*pr[2][2]) / fmaxf(lenN1*lenN2, 1e-8f);
    float angN_sq = angN0*angN0 + angN1*angN1 + angN2*angN2;
    float lenN_sq = lenN0*lenN0 + lenN1*lenN1 + lenN2*lenN2;

    double nei_sq = 0.0;
    #pragma unroll
    for (int i = 0; i < 24; ++i) {
        float4 v = xn4[i];
        nei_sq += (double)v.x*v.x + (double)v.y*v.y + (double)v.z*v.z + (double)v.w*v.w;
    }
    float edsq = 0.f;
    #pragma unroll
    for (int i = 0; i < 6; ++i) {
        float4 v = ed4[i];
        edsq = fmaf(v.x, v.x, edsq); edsq = fmaf(v.y, v.y, edsq);
        edsq = fmaf(v.z, v.z, edsq); edsq = fmaf(v.w, v.w, edsq);
    }
    float xfsq = 0.f;
    #pragma unroll
    for (int i = 0; i < 8; ++i) {
        float4 v = xf4[i];
        xfsq = fmaf(v.x, v.x, xfsq); xfsq = fmaf(v.y, v.y, xfsq);
        xfsq = fmaf(v.z, v.z, xfsq); xfsq = fmaf(v.w, v.w, xfsq);
    }

    // itertools.permutations((0,1,2)) order
    constexpr int PA[6] = {0, 0, 1, 1, 2, 2};
    constexpr int PB[6] = {1, 2, 0, 2, 0, 1};
    constexpr int PC[6] = {2, 1, 2, 0, 1, 0};

    for (int l = 0; l < L_; ++l) {
        const float* xs = s_xs[l];
        const float* es = s_es[l];
        const float* xc = s_xc[l];
        float lsv0 = s_scal[l][0], lsv1 = s_scal[l][1], lsv2 = s_scal[l][2];
        float Cm[3][3];
        Cm[0][1] = Cm[1][0] = s_scal[l][3];
        Cm[0][2] = Cm[2][0] = s_scal[l][4];
        Cm[1][2] = Cm[2][1] = s_scal[l][5];
        Cm[0][0] = Cm[1][1] = Cm[2][2] = 0.f;  // never used (perm neighbors distinct)
        float angS_sq = s_scal[l][6];
        float lenS_sq = s_scal[l][7];
        float sup_sq  = s_scal[l][8];
        float esS_sq  = s_scal[l][9];
        float xc_sq   = s_scal[l][10];
        float lsv[3] = {lsv0, lsv1, lsv2};

        // 9 support dot products, fp64 accumulation (argmax-critical)
        double cr[3][3] = {{0,0,0},{0,0,0},{0,0,0}};
        #pragma unroll
        for (int f4 = 0; f4 < 8; ++f4) {
            float4 B0 = ((const float4*)(xs +  0))[f4];
            float4 B1 = ((const float4*)(xs + 32))[f4];
            float4 B2 = ((const float4*)(xs + 64))[f4];
            float4 A0 = xn4[f4], A1 = xn4[8 + f4], A2 = xn4[16 + f4];
            CR_STEP(A0.x, A1.x, A2.x, B0.x, B1.x, B2.x)
            CR_STEP(A0.y, A1.y, A2.y, B0.y, B1.y, B2.y)
            CR_STEP(A0.z, A1.z, A2.z, B0.z, B1.z, B2.z)
            CR_STEP(A0.w, A1.w, A2.w, B0.w, B1.w, B2.w)
        }

        // 9 edge dot products, fp32 (value only)
        float er[3][3] = {{0,0,0},{0,0,0},{0,0,0}};
        #pragma unroll
        for (int e4 = 0; e4 < 2; ++e4) {
            float4 B0 = ((const float4*)(es +  0))[e4];
            float4 B1 = ((const float4*)(es +  8))[e4];
            float4 B2 = ((const float4*)(es + 16))[e4];
            float4 A0 = ed4[e4], A1 = ed4[2 + e4], A2 = ed4[4 + e4];
            ER_STEP(A0.x, A1.x, A2.x, B0.x, B1.x, B2.x)
            ER_STEP(A0.y, A1.y, A2.y, B0.y, B1.y, B2.y)
            ER_STEP(A0.z, A1.z, A2.z, B0.z, B1.z, B2.z)
            ER_STEP(A0.w, A1.w, A2.w, B0.w, B1.w, B2.w)
        }

        // center dot, fp32
        float cdot = 0.f;
        #pragma unroll
        for (int f4 = 0; f4 < 8; ++f4) {
            float4 B = ((const float4*)xc)[f4];
            float4 A = xf4[f4];
            cdot = fmaf(A.x, B.x, cdot); cdot = fmaf(A.y, B.y, cdot);
            cdot = fmaf(A.z, B.z, cdot); cdot = fmaf(A.w, B.w, cdot);
        }

        // argmax over 6 perms: max cross <=> min dist <=> max atan(1/dist)
        double bestCs = -1e300;
        float bestE = 0.f, bestA = 0.f, bestL = 0.f;
        #pragma unroll
        for (int p = 0; p < 6; ++p) {
            const int a = PA[p], b = PB[p], c = PC[p];
            double cs = cr[0][a] + cr[1][b] + cr[2][c];
            if (cs > bestCs) {   // strict > keeps first-max (jnp.argmax semantics)
                bestCs = cs;
                bestE = er[0][a] + er[1][b] + er[2][c];
                bestA = fmaf(angN0, Cm[c][a], fmaf(angN1, Cm[a][b], angN2 * Cm[b][c]));
                bestL = fmaf(lenN0, lsv[a], fmaf(lenN1, lsv[b], lenN2 * lsv[c]));
            }
        }

        double dist = nei_sq + (double)sup_sq - 2.0 * bestCs;
        float sup_sc  = atanf((float)(1.0 / dist));
        float edge_sc = atanf(1.0f / (edsq   + esS_sq  - 2.0f * bestE));
        float ang_sc  = atanf(1.0f / (angN_sq + angS_sq - 2.0f * bestA));
        float len_sc  = atanf(1.0f / (lenN_sq + lenS_sq - 2.0f * bestL));
        float cen_sc  = atanf(1.0f / (xfsq   + xc_sq   - 2.0f * cdot));

        float t1 = len_sc - HP, t2 = ang_sc - HP, t3 = sup_sc - HP;
        float t4 = cen_sc - HP, t5 = edge_sc - HP;
        float h = t1*t1 + t2*t2 + t3*t3 + t4*t4 + t5*t5;
        out[(size_t)l * N + n] = atanf(1.0f / h);
    }
}

extern "C" void kernel_launch(void* const* d_in, const int* in_sizes, int n_in,
                              void* d_out, int out_size, void* d_ws, size_t ws_size,
                              hipStream_t stream)
{
    const float* x_focal    = (const float*)d_in[0];
    const float* p_focal    = (const float*)d_in[1];
    const float* x_neighbor = (const float*)d_in[2];
    const float* p_neighbor = (const float*)d_in[3];
    const float* edge_nei   = (const float*)d_in[4];
    const float* x_center   = (const float*)d_in[5];
    const float* x_support  = (const float*)d_in[6];
    const float* edge_sup   = (const float*)d_in[7];
    const float* p_support  = (const float*)d_in[8];
    float* out = (float*)d_out;

    const int N = in_sizes[0] / F_;           // x_focal is (N, 32)
    const int threads = 128;
    const int blocks = (N + threads - 1) / threads;
    setconv_kernel<<<blocks, threads, 0, stream>>>(
        x_focal, p_focal, x_neighbor, p_neighbor, edge_nei,
        x_center, x_support, edge_sup, p_support, out, N);
}

// Round 2
// 209.154 us; speedup vs baseline: 38.5418x; 38.5418x over previous
//
#include <hip/hip_runtime.h>
#include <math.h>

#define L_ 64
#define HPf 1.57079632679489661923f

// 9-way fp64 accumulate: cr[m][k] += a_m * b_k (all compile-time indices)
// NOTE: FMA order identical to the round-1 kernel so the argmax ranking
// (and therefore the passing absmax) is bit-identical.
#define CR_STEP(a0, a1, a2, b0, b1, b2)                          \
    cr[0][0] = fma((double)(a0), (double)(b0), cr[0][0]);        \
    cr[0][1] = fma((double)(a0), (double)(b1), cr[0][1]);        \
    cr[0][2] = fma((double)(a0), (double)(b2), cr[0][2]);        \
    cr[1][0] = fma((double)(a1), (double)(b0), cr[1][0]);        \
    cr[1][1] = fma((double)(a1), (double)(b1), cr[1][1]);        \
    cr[1][2] = fma((double)(a1), (double)(b2), cr[1][2]);        \
    cr[2][0] = fma((double)(a2), (double)(b0), cr[2][0]);        \
    cr[2][1] = fma((double)(a2), (double)(b1), cr[2][1]);        \
    cr[2][2] = fma((double)(a2), (double)(b2), cr[2][2]);

#define ER_STEP(a0, a1, a2, b0, b1, b2)                          \
    er[0][0] = fmaf((a0), (b0), er[0][0]);                       \
    er[0][1] = fmaf((a0), (b1), er[0][1]);                       \
    er[0][2] = fmaf((a0), (b2), er[0][2]);                       \
    er[1][0] = fmaf((a1), (b0), er[1][0]);                       \
    er[1][1] = fmaf((a1), (b1), er[1][1]);                       \
    er[1][2] = fmaf((a1), (b2), er[1][2]);                       \
    er[2][0] = fmaf((a2), (b0), er[2][0]);                       \
    er[2][1] = fmaf((a2), (b1), er[2][1]);                       \
    er[2][2] = fmaf((a2), (b2), er[2][2]);

// ---------------- Kernel A: support argmax (fp64-critical) ----------------
// Per (l,n): 9 fp64 dots over F=32 between neighbor rows and support rows,
// argmax over 6 permutation sums, write (sup_sc - pi/2)^2 to out and the
// packed winning permutation (a<<4|b<<2|c) to bestp.
// waves_per_eu(2,2): pins the occupancy target at 2 waves/SIMD -> 256-VGPR
// budget, so the ~150-reg live set (xn=96 + cr=18 + tiles) does NOT spill.
__global__ __attribute__((amdgpu_waves_per_eu(2, 2))) __launch_bounds__(128)
void setconvA(const float* __restrict__ x_neighbor,
              const float* __restrict__ x_support,
              float* __restrict__ out,
              unsigned char* __restrict__ bestp,
              int N)
{
    __shared__ __align__(16) float s_xs[L_ * 96];
    __shared__ float s_ssq[L_];

    const int tid = threadIdx.x;
    for (int i = tid; i < L_ * 96 / 4; i += 128)
        ((float4*)s_xs)[i] = ((const float4*)x_support)[i];
    __syncthreads();
    if (tid < L_) {
        const float* row = s_xs + tid * 96;
        double ssq = 0.0;
        for (int i = 0; i < 96; ++i) { double v = (double)row[i]; ssq += v * v; }
        s_ssq[tid] = (float)ssq;
    }
    __syncthreads();

    const int n = blockIdx.x * 128 + tid;
    if (n >= N) return;

    float4 xn4[24];
    {
        const float4* p = (const float4*)(x_neighbor + (size_t)n * 96);
        #pragma unroll
        for (int i = 0; i < 24; ++i) xn4[i] = p[i];
    }
    double nei_sq = 0.0;
    #pragma unroll
    for (int i = 0; i < 24; ++i) {
        float4 v = xn4[i];
        nei_sq += (double)v.x*v.x + (double)v.y*v.y + (double)v.z*v.z + (double)v.w*v.w;
    }

    // itertools.permutations((0,1,2)) order; packed byte = a<<4 | b<<2 | c
    constexpr int PA[6] = {0, 0, 1, 1, 2, 2};
    constexpr int PB[6] = {1, 2, 0, 2, 0, 1};
    constexpr int PC[6] = {2, 1, 2, 0, 1, 0};
    constexpr int PK[6] = {6, 9, 18, 24, 33, 36};

    for (int l = 0; l < L_; ++l) {
        const float* xs = s_xs + l * 96;
        double cr[3][3] = {{0,0,0},{0,0,0},{0,0,0}};
        #pragma unroll
        for (int f4 = 0; f4 < 8; ++f4) {
            float4 B0 = ((const float4*)(xs +  0))[f4];
            float4 B1 = ((const float4*)(xs + 32))[f4];
            float4 B2 = ((const float4*)(xs + 64))[f4];
            float4 A0 = xn4[f4], A1 = xn4[8 + f4], A2 = xn4[16 + f4];
            CR_STEP(A0.x, A1.x, A2.x, B0.x, B1.x, B2.x)
            CR_STEP(A0.y, A1.y, A2.y, B0.y, B1.y, B2.y)
            CR_STEP(A0.z, A1.z, A2.z, B0.z, B1.z, B2.z)
            CR_STEP(A0.w, A1.w, A2.w, B0.w, B1.w, B2.w)
        }

        double bestCs = -1e300;
        int bpk = 0;
        #pragma unroll
        for (int p = 0; p < 6; ++p) {
            double cs = cr[0][PA[p]] + cr[1][PB[p]] + cr[2][PC[p]];
            if (cs > bestCs) { bestCs = cs; bpk = PK[p]; }  // strict >: first max
        }

        double dist = nei_sq + (double)s_ssq[l] - 2.0 * bestCs;
        float sup_sc = atanf((float)(1.0 / dist));
        float t3 = sup_sc - HPf;
        size_t idx = (size_t)l * N + n;
        out[idx]   = t3 * t3;
        bestp[idx] = (unsigned char)bpk;
    }
}

// ---------------- Kernel B: value-only scores (fp32) ----------------
// Reads the winning perm byte, computes edge/angle/length/center scores,
// accumulates into out and applies the final atan(1/h).
__global__ __attribute__((amdgpu_waves_per_eu(3, 4))) __launch_bounds__(128)
void setconvB(const float* __restrict__ x_focal,
              const float* __restrict__ p_focal,
              const float* __restrict__ p_neighbor,
              const float* __restrict__ edge_nei,
              const float* __restrict__ x_center,
              const float* __restrict__ edge_sup,
              const float* __restrict__ p_support,
              const unsigned char* __restrict__ bestp,
              float* __restrict__ out,
              int N)
{
    __shared__ __align__(16) float s_es[L_ * 24];
    __shared__ __align__(16) float s_xc[L_ * 32];
    __shared__ float s_scal[L_][10];

    const int tid = threadIdx.x;
    for (int i = tid; i < L_ * 24 / 4; i += 128)
        ((float4*)s_es)[i] = ((const float4*)edge_sup)[i];
    for (int i = tid; i < L_ * 32 / 4; i += 128)
        ((float4*)s_xc)[i] = ((const float4*)x_center)[i];
    __syncthreads();

    if (tid < L_) {
        const int l = tid;
        float esq = 0.f;
        for (int i = 0; i < 24; ++i) esq = fmaf(s_es[l*24 + i], s_es[l*24 + i], esq);
        float csq = 0.f;
        for (int i = 0; i < 32; ++i) csq = fmaf(s_xc[l*32 + i], s_xc[l*32 + i], csq);

        float p0[3], p1[3], p2[3];
        for (int d = 0; d < 3; ++d) {
            p0[d] = p_support[(l * 3 + 0) * 3 + d];
            p1[d] = p_support[(l * 3 + 1) * 3 + d];
            p2[d] = p_support[(l * 3 + 2) * 3 + d];
        }
        float n0 = sqrtf(p0[0]*p0[0] + p0[1]*p0[1] + p0[2]*p0[2]);
        float n1 = sqrtf(p1[0]*p1[0] + p1[1]*p1[1] + p1[2]*p1[2]);
        float n2 = sqrtf(p2[0]*p2[0] + p2[1]*p2[1] + p2[2]*p2[2]);
        float d01 = p0[0]*p1[0] + p0[1]*p1[1] + p0[2]*p1[2];
        float d02 = p0[0]*p2[0] + p0[1]*p2[1] + p0[2]*p2[2];
        float d12 = p1[0]*p2[0] + p1[1]*p2[1] + p1[2]*p2[2];
        float C01 = d01 / fmaxf(n0 * n1, 1e-8f);
        float C02 = d02 / fmaxf(n0 * n2, 1e-8f);
        float C12 = d12 / fmaxf(n1 * n2, 1e-8f);

        s_scal[l][0] = n0;  s_scal[l][1] = n1;  s_scal[l][2] = n2;
        s_scal[l][3] = C01; s_scal[l][4] = C02; s_scal[l][5] = C12;
        s_scal[l][6] = C01*C01 + C02*C02 + C12*C12;   // ang_sup sq-sum (p-invariant)
        s_scal[l][7] = n0*n0 + n1*n1 + n2*n2;         // len_sup sq-sum (p-invariant)
        s_scal[l][8] = esq;
        s_scal[l][9] = csq;
    }
    __syncthreads();

    const int n = blockIdx.x * 128 + tid;
    if (n >= N) return;

    float4 ed4[6], xf4[8];
    {
        const float4* q = (const float4*)(edge_nei + (size_t)n * 24);
        #pragma unroll
        for (int i = 0; i < 6; ++i) ed4[i] = q[i];
        const float4* r = (const float4*)(x_focal + (size_t)n * 32);
        #pragma unroll
        for (int i = 0; i < 8; ++i) xf4[i] = r[i];
    }

    // p_rel, intra angles, lengths
    float pr[3][3];
    {
        float pf0 = p_focal[(size_t)n*3 + 0];
        float pf1 = p_focal[(size_t)n*3 + 1];
        float pf2 = p_focal[(size_t)n*3 + 2];
        #pragma unroll
        for (int m = 0; m < 3; ++m) {
            pr[m][0] = p_neighbor[(size_t)n*9 + m*3 + 0] - pf0;
            pr[m][1] = p_neighbor[(size_t)n*9 + m*3 + 1] - pf1;
            pr[m][2] = p_neighbor[(size_t)n*9 + m*3 + 2] - pf2;
        }
    }
    float lenN0 = sqrtf(pr[0][0]*pr[0][0] + pr[0][1]*pr[0][1] + pr[0][2]*pr[0][2]);
    float lenN1 = sqrtf(pr[1][0]*pr[1][0] + pr[1][1]*pr[1][1] + pr[1][2]*pr[1][2]);
    float lenN2 = sqrtf(pr[2][0]*pr[2][0] + pr[2][1]*pr[2][1] + pr[2][2]*pr[2][2]);
    float angN0 = (pr[2][0]*pr[0][0] + pr[2][1]*pr[0][1] + pr[2][2]*pr[0][2]) / fmaxf(lenN2*lenN0, 1e-8f);
    float angN1 = (pr[0][0]*pr[1][0] + pr[0][1]*pr[1][1] + pr[0][2]*pr[1][2]) / fmaxf(lenN0*lenN1, 1e-8f);
    float angN2 = (pr[1][0]*pr[2][0] + pr[1][1]*pr[2][1] + pr[1][2]*pr[2][2]) / fmaxf(lenN1*lenN2, 1e-8f);
    float angN_sq = angN0*angN0 + angN1*angN1 + angN2*angN2;
    float lenN_sq = lenN0*lenN0 + lenN1*lenN1 + lenN2*lenN2;

    float edsq = 0.f;
    #pragma unroll
    for (int i = 0; i < 6; ++i) {
        float4 v = ed4[i];
        edsq = fmaf(v.x, v.x, edsq); edsq = fmaf(v.y, v.y, edsq);
        edsq = fmaf(v.z, v.z, edsq); edsq = fmaf(v.w, v.w, edsq);
    }
    float xfsq = 0.f;
    #pragma unroll
    for (int i = 0; i < 8; ++i) {
        float4 v = xf4[i];
        xfsq = fmaf(v.x, v.x, xfsq); xfsq = fmaf(v.y, v.y, xfsq);
        xfsq = fmaf(v.z, v.z, xfsq); xfsq = fmaf(v.w, v.w, xfsq);
    }

    for (int l = 0; l < L_; ++l) {
        const float* es = s_es + l * 24;
        const float* xc = s_xc + l * 32;

        float er[3][3] = {{0,0,0},{0,0,0},{0,0,0}};
        #pragma unroll
        for (int e4 = 0; e4 < 2; ++e4) {
            float4 B0 = ((const float4*)(es +  0))[e4];
            float4 B1 = ((const float4*)(es +  8))[e4];
            float4 B2 = ((const float4*)(es + 16))[e4];
            float4 A0 = ed4[e4], A1 = ed4[2 + e4], A2 = ed4[4 + e4];
            ER_STEP(A0.x, A1.x, A2.x, B0.x, B1.x, B2.x)
            ER_STEP(A0.y, A1.y, A2.y, B0.y, B1.y, B2.y)
            ER_STEP(A0.z, A1.z, A2.z, B0.z, B1.z, B2.z)
            ER_STEP(A0.w, A1.w, A2.w, B0.w, B1.w, B2.w)
        }

        float cdot = 0.f;
        #pragma unroll
        for (int f4 = 0; f4 < 8; ++f4) {
            float4 B = ((const float4*)xc)[f4];
            float4 A = xf4[f4];
            cdot = fmaf(A.x, B.x, cdot); cdot = fmaf(A.y, B.y, cdot);
            cdot = fmaf(A.z, B.z, cdot); cdot = fmaf(A.w, B.w, cdot);
        }

        size_t idx = (size_t)l * N + n;
        int bp = bestp[idx];
        int a = (bp >> 4) & 3, b = (bp >> 2) & 3, c = bp & 3;

        // selects with compile-time array indices only (no scratch risk)
        float e0 = (a == 0) ? er[0][0] : ((a == 1) ? er[0][1] : er[0][2]);
        float e1 = (b == 0) ? er[1][0] : ((b == 1) ? er[1][1] : er[1][2]);
        float e2 = (c == 0) ? er[2][0] : ((c == 1) ? er[2][1] : er[2][2]);
        float bestE = e0 + e1 + e2;

        float n0 = s_scal[l][0], n1 = s_scal[l][1], n2 = s_scal[l][2];
        float C01 = s_scal[l][3], C02 = s_scal[l][4], C12 = s_scal[l][5];
        float la = (a == 0) ? n0 : ((a == 1) ? n1 : n2);
        float lb = (b == 0) ? n0 : ((b == 1) ? n1 : n2);
        float lc = (c == 0) ? n0 : ((c == 1) ? n1 : n2);
        float bestL = fmaf(lenN0, la, fmaf(lenN1, lb, lenN2 * lc));

        int sca = c + a, sab = a + b, sbc = b + c;            // in {1,2,3}
        float Cca = (sca == 1) ? C01 : ((sca == 2) ? C02 : C12);
        float Cab = (sab == 1) ? C01 : ((sab == 2) ? C02 : C12);
        float Cbc = (sbc == 1) ? C01 : ((sbc == 2) ? C02 : C12);
        float bestA = fmaf(angN0, Cca, fmaf(angN1, Cab, angN2 * Cbc));

        float edge_sc = atanf(1.0f / (edsq    + s_scal[l][8] - 2.0f * bestE));
        float ang_sc  = atanf(1.0f / (angN_sq + s_scal[l][6] - 2.0f * bestA));
        float len_sc  = atanf(1.0f / (lenN_sq + s_scal[l][7] - 2.0f * bestL));
        float cen_sc  = atanf(1.0f / (xfsq    + s_scal[l][9] - 2.0f * cdot));

        float t1 = len_sc - HPf, t2 = ang_sc - HPf, t4 = cen_sc - HPf, t5 = edge_sc - HPf;
        float h = out[idx] + t1*t1 + t2*t2 + t4*t4 + t5*t5;
        out[idx] = atanf(1.0f / h);
    }
}

extern "C" void kernel_launch(void* const* d_in, const int* in_sizes, int n_in,
                              void* d_out, int out_size, void* d_ws, size_t ws_size,
                              hipStream_t stream)
{
    const float* x_focal    = (const float*)d_in[0];
    const float* p_focal    = (const float*)d_in[1];
    const float* x_neighbor = (const float*)d_in[2];
    const float* p_neighbor = (const float*)d_in[3];
    const float* edge_nei   = (const float*)d_in[4];
    const float* x_center   = (const float*)d_in[5];
    const float* x_support  = (const float*)d_in[6];
    const float* edge_sup   = (const float*)d_in[7];
    const float* p_support  = (const float*)d_in[8];
    float* out = (float*)d_out;
    unsigned char* bestp = (unsigned char*)d_ws;   // L*N bytes = 6.4 MB

    const int N = in_sizes[0] / 32;                // x_focal is (N, 32)
    const int threads = 128;
    const int blocks = (N + threads - 1) / threads;

    setconvA<<<blocks, threads, 0, stream>>>(x_neighbor, x_support, out, bestp, N);
    setconvB<<<blocks, threads, 0, stream>>>(x_focal, p_focal, p_neighbor, edge_nei,
                                             x_center, edge_sup, p_support, bestp, out, N);
}